// Round 1
// 273.964 us; speedup vs baseline: 1.0108x; 1.0108x over previous
//
#include <hip/hip_runtime.h>
#include <hip/hip_bf16.h>

// Problem constants
#define Bb 256
#define Tt 128
#define Nn 512
#define Hh 128
// 4H = 512

typedef __attribute__((ext_vector_type(4))) float floatx4;
typedef __attribute__((ext_vector_type(8))) short short8;
typedef _Float16 h2v_t __attribute__((ext_vector_type(2)));

__device__ __forceinline__ unsigned short f2bf(float f) {
  unsigned u = __float_as_uint(f);
  u += 0x7fffu + ((u >> 16) & 1u);   // round-to-nearest-even
  return (unsigned short)(u >> 16);
}

// Fast activations: v_exp + v_rcp (~1ulp each) instead of IEEE div sequences.
__device__ __forceinline__ float sigmoid_fast(float x) {
  return __builtin_amdgcn_rcpf(1.f + __expf(-x));
}
__device__ __forceinline__ float tanh_fast(float x) {
  float e = __expf(2.f * x);                       // inf-safe
  return 1.f - 2.f * __builtin_amdgcn_rcpf(e + 1.f);
}

// Workgroup barrier that does NOT drain vmcnt: only LDS ops are waited.
// Global loads/stores issued before it stay in flight across the barrier.
__device__ __forceinline__ void lds_barrier() {
  asm volatile("s_waitcnt lgkmcnt(0)" ::: "memory");
  __builtin_amdgcn_s_barrier();
  asm volatile("" ::: "memory");
}

__device__ __forceinline__ void async_load16(const void* g, void* lds) {
  __builtin_amdgcn_global_load_lds(
      (const __attribute__((address_space(1))) unsigned int*)g,
      (__attribute__((address_space(3))) unsigned int*)lds, 16, 0, 0);
}

// 2-MAC-per-lane fp16 dot with fp32 accumulate (v_dot2_f32_f16).
#if __has_builtin(__builtin_amdgcn_fdot2)
#define FDOT2(a, b, c) __builtin_amdgcn_fdot2((a), (b), (c), false)
#else
__device__ __forceinline__ float fdot2_sw(h2v_t a, h2v_t b, float c) {
  return fmaf((float)a.x, (float)b.x, fmaf((float)a.y, (float)b.y, (c)));
}
#define FDOT2(a, b, c) fdot2_sw((a), (b), (c))
#endif

// Quad-permute via DPP (VALU-speed cross-lane within groups of 4 lanes).
// 0xB1 = quad_perm [1,0,3,2] (xor 1); 0x4E = quad_perm [2,3,0,1] (xor 2).
template <int CTRL>
__device__ __forceinline__ float qperm(float x) {
#if __has_builtin(__builtin_amdgcn_update_dpp)
  return __uint_as_float((unsigned)__builtin_amdgcn_update_dpp(
      0, (int)__float_as_uint(x), CTRL, 0xf, 0xf, true));
#else
  return __shfl_xor(x, CTRL == 0xB1 ? 1 : 2, 64);
#endif
}

// ---------------------------------------------------------------------------
// Kernel 1: convert w_ih to bf16, precompute bias = b_ih + b_hh
// ---------------------------------------------------------------------------
__global__ void prep_kernel(const float* __restrict__ w_ih,
                            const float* __restrict__ b_ih,
                            const float* __restrict__ b_hh,
                            unsigned short* __restrict__ wb,
                            float* __restrict__ bias) {
  int i = blockIdx.x * 256 + threadIdx.x;
  if (i < 4 * Hh * Nn) wb[i] = f2bf(w_ih[i]);
  if (i < 4 * Hh) bias[i] = b_ih[i] + b_hh[i];
}

// ---------------------------------------------------------------------------
// Kernel 2: alpha[b,n] = softmax_n( sum_t X[b,t,n] * w_x[t] )
// (softmax shift-invariance kills the h/c-dependent scalar term)
// ---------------------------------------------------------------------------
__global__ __launch_bounds__(512) void alpha_kernel(const float* __restrict__ X,
                                                    const float* __restrict__ attn_w,
                                                    float* __restrict__ alpha) {
  int b = blockIdx.x;
  int n = threadIdx.x;                     // 512 threads
  const float* Xb = X + (size_t)b * Tt * Nn + n;
  float acc = 0.f;
#pragma unroll 8
  for (int t = 0; t < Tt; ++t)
    acc = fmaf(Xb[(size_t)t * Nn], attn_w[2 * Hh + t], acc);

  __shared__ float red[512];
  red[n] = acc;
  __syncthreads();
  for (int s = 256; s > 0; s >>= 1) {
    if (n < s) red[n] = fmaxf(red[n], red[n + s]);
    __syncthreads();
  }
  float m = red[0];
  __syncthreads();
  float e = __expf(acc - m);
  red[n] = e;
  __syncthreads();
  for (int s = 256; s > 0; s >>= 1) {
    if (n < s) red[n] += red[n + s];
    __syncthreads();
  }
  alpha[(size_t)b * Nn + n] = e / red[0];
}

// ---------------------------------------------------------------------------
// Kernel 3: Xt = alpha * X (fp32, output 0) and xtb = bf16(Xt) for the GEMM
// ---------------------------------------------------------------------------
__global__ __launch_bounds__(256) void scale_kernel(const float* __restrict__ X,
                                                    const float* __restrict__ alpha,
                                                    float* __restrict__ Xt,
                                                    unsigned short* __restrict__ xtb) {
  size_t i = (size_t)blockIdx.x * 256 + threadIdx.x;  // float4 index; grid is exact
  size_t e = i * 4;
  int n = (int)(e & (Nn - 1));
  int brow = (int)(e >> 9);   // b*T + t
  int b = brow >> 7;          // T = 128
  float4 x = ((const float4*)X)[i];
  float4 a = *(const float4*)(alpha + (size_t)b * Nn + n);
  float4 y;
  y.x = x.x * a.x; y.y = x.y * a.y; y.z = x.z * a.z; y.w = x.w * a.w;
  ((float4*)Xt)[i] = y;
  ushort4 u;
  u.x = f2bf(y.x); u.y = f2bf(y.y); u.z = f2bf(y.z); u.w = f2bf(y.w);
  ((ushort4*)xtb)[i] = u;
}

// ---------------------------------------------------------------------------
// Kernel 4: G[m, j] = sum_k xtb[m,k] * w_ih[j,k] + bias[j]   (bf16 MFMA)
// M = B*T = 32768, N = 512, K = 512. B^T layout (w_ih rows are k-contiguous).
// 128x128 block tile, 4 waves 2x2, 64x64/wave via 4x4 frags of 16x16x32.
// Staging via global_load_lds (16B) into XOR-swizzled LDS:
//   LDS chunk s (16B) of row r holds global k-chunk  s ^ (r & 7).
// Wave-slot: wave w stages rows r0 = slot*32 + w*8 (1024 B contiguous LDS);
// lane l -> row r0 + (l>>3), LDS chunk l&7, so global chunk (l&7)^(l>>3).
// MFMA reads row (…+l15), k-chunk (quad + 4*kh): LDS chunk = that ^ (l15&7)
// -> 2 lanes/bank max (free per m136). No pad, 16 KB per array.
// ---------------------------------------------------------------------------
#define GBK 64

__global__ __launch_bounds__(256) void gemm_bt(const unsigned short* __restrict__ A,
                                               const unsigned short* __restrict__ Bw,
                                               const float* __restrict__ bias,
                                               float* __restrict__ C) {
  __shared__ __align__(16) unsigned short As[128 * 64];
  __shared__ __align__(16) unsigned short Bs[128 * 64];
  const int K = 512, NO = 512;
  int tid = threadIdx.x;
  int lane = tid & 63;
  int wave = tid >> 6;
  int wm = wave & 1, wn = wave >> 1;
  int l15 = lane & 15;
  int quad = lane >> 4;
  int mtile = blockIdx.x, ntile = blockIdx.y;

  floatx4 acc[4][4];
#pragma unroll
  for (int i = 0; i < 4; ++i)
#pragma unroll
    for (int j = 0; j < 4; ++j) acc[i][j] = (floatx4){0.f, 0.f, 0.f, 0.f};

  // staging addresses
  int lr = lane >> 3;                 // local row within wave-slot (0..7)
  int lc = (lane & 7) ^ lr;           // swizzled global k-chunk for this lane
  const size_t lane_goff = (size_t)lr * K + lc * 8;
  const size_t abase = (size_t)mtile * 128 * K + lane_goff;
  const size_t bbase = (size_t)ntile * 128 * K + lane_goff;
  // MFMA read swizzle (lane-static)
  int sw = (quad ^ (l15 & 7)) * 8;    // element offset of chunk for kh=0

  for (int kb = 0; kb < K; kb += GBK) {
#pragma unroll
    for (int slot = 0; slot < 4; ++slot) {
      int r0 = slot * 32 + wave * 8;
      async_load16(A + abase + (size_t)r0 * K + kb, &As[r0 * 64]);
      async_load16(Bw + bbase + (size_t)r0 * K + kb, &Bs[r0 * 64]);
    }
    __syncthreads();   // drains vmcnt(0): LDS-DMA complete
#pragma unroll
    for (int kh = 0; kh < 2; ++kh) {
      int sc = sw ^ (kh * 32);        // ^ (4 chunks * 8 elem)
      short8 af[4], bf[4];
#pragma unroll
      for (int i = 0; i < 4; ++i)
        af[i] = *(const short8*)(&As[(wm * 64 + i * 16 + l15) * 64 + sc]);
#pragma unroll
      for (int j = 0; j < 4; ++j)
        bf[j] = *(const short8*)(&Bs[(wn * 64 + j * 16 + l15) * 64 + sc]);
#pragma unroll
      for (int i = 0; i < 4; ++i)
#pragma unroll
        for (int j = 0; j < 4; ++j)
          acc[i][j] = __builtin_amdgcn_mfma_f32_16x16x32_bf16(af[i], bf[j], acc[i][j], 0, 0, 0);
    }
    __syncthreads();
  }

  // Epilogue: C/D mapping col = lane&15 (n), row = quad*4 + reg (m)
  int m0 = mtile * 128 + wm * 64;
  int n0 = ntile * 128 + wn * 64;
#pragma unroll
  for (int j = 0; j < 4; ++j) {
    int col = n0 + j * 16 + l15;
    float bsum = bias[col];
#pragma unroll
    for (int i = 0; i < 4; ++i) {
      int row = m0 + i * 16 + quad * 4;
#pragma unroll
      for (int r = 0; r < 4; ++r)
        C[(size_t)(row + r) * NO + col] = acc[i][j][r] + bsum;
    }
  }
}

// ---------------------------------------------------------------------------
// Kernel 5: sequential LSTM — VALU v_dot2_f32_f16 recurrence (no MFMA).
// The MFMA version replicated one h into all 16 A-rows (16x waste): a hard
// 620 cyc/SIMD/step issue floor. Useful work is only 1x128 @ 128x512 =
// 131 KFLOP/step/CU -> on the VALU with dot2 (2 MAC/lane) that is 64 dot2
// per thread, ~256 cyc/SIMD/step issue for the 2 resident waves.
//
// Thread j = 4u+q owns unit u (0..127), k-quarter q (0..3):
//  - persistent VGPR weights: w_hh[f*128+u][32q..32q+32) fp16-packed, 64 regs
//  - h kept fp16 in LDS (2x256 B double buffer); 4 broadcast ds_read_b128
//    per lane per step (2-way bank alias = free)
//  - k-reduction across the 4 lanes of the hardware quad via DPP quad_perm
//    (no LDS, no extra barrier); G bias folds in pre-reduction: lane q seeds
//    its gate-q partial with G[q*128+u], so each gate total gets G exactly once
//  - nonlinearity is unit-local (all 4 gates in-lane), replicated x4; q==0
//    commits h (fp16 -> LDS) and Xe. Single lgkmcnt-only barrier per step;
//    G prefetched 2 steps ahead (stays in flight across the barrier).
// ---------------------------------------------------------------------------
__global__ __launch_bounds__(512, 1) void lstm_kernel(const float* __restrict__ G,
                                                      const float* __restrict__ w_hh,
                                                      float* __restrict__ Xe) {
  int b = blockIdx.x;
  int tid = threadIdx.x;
  int u = tid >> 2;      // unit 0..127
  int q = tid & 3;       // k-quarter / gate-bias slot

  // Preload this lane's w_hh slice: rows f*128+u, cols [32q, 32q+32), fp16.
  h2v_t wreg[4][16];
#pragma unroll
  for (int f = 0; f < 4; ++f) {
    const float4* wr = (const float4*)(w_hh + ((size_t)(f * 128 + u) * 128 + q * 32));
#pragma unroll
    for (int i = 0; i < 8; ++i) {
      float4 v = wr[i];
      wreg[f][2 * i]     = (h2v_t){(_Float16)v.x, (_Float16)v.y};
      wreg[f][2 * i + 1] = (h2v_t){(_Float16)v.z, (_Float16)v.w};
    }
  }

  __shared__ __align__(16) unsigned short h2[2][128];   // fp16 h, double-buffered
  if (tid < 128) h2[0][tid] = 0;
  __syncthreads();

  const float* Gb = G + (size_t)b * Tt * 512 + q * 128 + u;
  float* Xeb = Xe + (size_t)b * Tt * Hh;

  float gcur = Gb[0];
  float gnext = Gb[512];
  float c0 = 0.f;

  for (int t = 0; t < Tt; ++t) {
    int cur = t & 1;
    // Broadcast-read this lane's h quarter: bytes [64q, 64q+64) of buf[cur].
    const uint4* hp = (const uint4*)(&h2[cur][0]) + q * 4;
    uint4 ha = hp[0], hb = hp[1], hc = hp[2], hd = hp[3];

    float g_this = gcur;
    gcur = gnext;
    if (t + 2 < Tt) gnext = Gb[(size_t)(t + 2) * 512];   // in flight across barrier

    float pg0 = (q == 0) ? g_this : 0.f;
    float pg1 = (q == 1) ? g_this : 0.f;
    float pg2 = (q == 2) ? g_this : 0.f;
    float pg3 = (q == 3) ? g_this : 0.f;

#define DOTK(HB, K2)                                                \
  {                                                                 \
    h2v_t hh = __builtin_bit_cast(h2v_t, (HB));                     \
    pg0 = FDOT2(hh, wreg[0][K2], pg0);                              \
    pg1 = FDOT2(hh, wreg[1][K2], pg1);                              \
    pg2 = FDOT2(hh, wreg[2][K2], pg2);                              \
    pg3 = FDOT2(hh, wreg[3][K2], pg3);                              \
  }
    DOTK(ha.x, 0)  DOTK(ha.y, 1)  DOTK(ha.z, 2)  DOTK(ha.w, 3)
    DOTK(hb.x, 4)  DOTK(hb.y, 5)  DOTK(hb.z, 6)  DOTK(hb.w, 7)
    DOTK(hc.x, 8)  DOTK(hc.y, 9)  DOTK(hc.z, 10) DOTK(hc.w, 11)
    DOTK(hd.x, 12) DOTK(hd.y, 13) DOTK(hd.z, 14) DOTK(hd.w, 15)
#undef DOTK

    // Sum k-quarters across the 4 lanes of this quad (DPP butterfly).
    pg0 += qperm<0xB1>(pg0); pg1 += qperm<0xB1>(pg1);
    pg2 += qperm<0xB1>(pg2); pg3 += qperm<0xB1>(pg3);
    pg0 += qperm<0x4E>(pg0); pg1 += qperm<0x4E>(pg1);
    pg2 += qperm<0x4E>(pg2); pg3 += qperm<0x4E>(pg3);

    float si = sigmoid_fast(pg0);
    float sf = sigmoid_fast(pg1);
    float tg = tanh_fast(pg2);
    float so = sigmoid_fast(pg3);
    c0 = sf * c0 + si * tg;
    float hv = so * tanh_fast(c0);

    if (q == 0) {
      Xeb[(size_t)t * Hh + u] = hv;                       // fire-and-forget
      h2[cur ^ 1][u] = __builtin_bit_cast(unsigned short, (_Float16)hv);
    }
    lds_barrier();   // LDS-only drain; G loads / Xe stores stay in flight
  }
}

// ---------------------------------------------------------------------------
extern "C" void kernel_launch(void* const* d_in, const int* in_sizes, int n_in,
                              void* d_out, int out_size, void* d_ws, size_t ws_size,
                              hipStream_t stream) {
  const float* X      = (const float*)d_in[0];
  const float* attn_w = (const float*)d_in[1];
  // d_in[2] = attn_b: cancels in softmax, unused
  const float* w_ih   = (const float*)d_in[3];
  const float* w_hh   = (const float*)d_in[4];
  const float* b_ih   = (const float*)d_in[5];
  const float* b_hh   = (const float*)d_in[6];

  float* Xt = (float*)d_out;                                  // (B,T,N)
  float* Xe = (float*)d_out + (size_t)Bb * Tt * Nn;           // (B,T,H)

  char* ws = (char*)d_ws;
  float*          alpha = (float*)(ws);                        //   512 KB
  float*          bias  = (float*)(ws + 524288);               //     2 KB
  unsigned short* wb    = (unsigned short*)(ws + 526336);      //   512 KB
  unsigned short* xtb   = (unsigned short*)(ws + 1050624);     //    32 MB
  float*          G     = (float*)(ws + 34605056);             //    64 MB
  // total ws use ~97 MB

  prep_kernel<<<dim3(1024), dim3(256), 0, stream>>>(w_ih, b_ih, b_hh, wb, bias);
  alpha_kernel<<<dim3(Bb), dim3(512), 0, stream>>>(X, attn_w, alpha);
  scale_kernel<<<dim3(16384), dim3(256), 0, stream>>>(X, alpha, Xt, xtb);
  gemm_bt<<<dim3(256, 4), dim3(256), 0, stream>>>(xtb, wb, bias, G);
  lstm_kernel<<<dim3(Bb), dim3(512), 0, stream>>>(G, w_hh, Xe);
}